// Round 2
// baseline (763.436 us; speedup 1.0000x reference)
//
#include <hip/hip_runtime.h>

// 3-layer GCN + mean pool, fp32.
// Pipeline per launch:
//   deg (atomic) -> dinv -> exclusive scan -> CSR scatter
//   L1: agg30(x) -> gemm30 (+b1, relu)
//   L2: agg128   -> gemm128(+b2, relu)
//   L3: agg128   -> gemm128(+b3, relu)
//   mean-pool via sorted batch_idx binary search (no atomics)
// Identity used: S(XW) = (SX)W  (S = D^-1/2 (A+I) D^-1/2 is linear)

#define DIN 30
#define HD  128

// ---------------- preprocessing ----------------
__global__ void k_zero_i32(int* __restrict__ p, int n) {
  int i = blockIdx.x * blockDim.x + threadIdx.x;
  if (i < n) p[i] = 0;
}

__global__ void k_degree(const int* __restrict__ dst, int* __restrict__ deg, int E) {
  int e = blockIdx.x * blockDim.x + threadIdx.x;
  if (e < E) atomicAdd(&deg[dst[e]], 1);
}

__global__ void k_dinv(const int* __restrict__ deg, float* __restrict__ dinv, int N) {
  int i = blockIdx.x * blockDim.x + threadIdx.x;
  if (i < N) dinv[i] = rsqrtf((float)(1 + deg[i]));  // self-loop included
}

// block scan over chunks of 1024 (256 threads x 4 elems)
__global__ void k_scan1(const int* __restrict__ deg, int* __restrict__ bsum, int N) {
  __shared__ int s[256];
  int tid = threadIdx.x;
  int base = blockIdx.x * 1024 + tid * 4;
  int t = 0;
#pragma unroll
  for (int j = 0; j < 4; ++j) { int idx = base + j; if (idx < N) t += deg[idx]; }
  s[tid] = t; __syncthreads();
  for (int d = 128; d > 0; d >>= 1) { if (tid < d) s[tid] += s[tid + d]; __syncthreads(); }
  if (tid == 0) bsum[blockIdx.x] = s[0];
}

// exclusive scan of block sums (assumes nb <= 256; N=200k -> nb=196)
__global__ void k_scan2(const int* __restrict__ bsum, int* __restrict__ boff, int nb) {
  __shared__ int s[256];
  int tid = threadIdx.x;
  int v = (tid < nb) ? bsum[tid] : 0;
  s[tid] = v; __syncthreads();
  for (int d = 1; d < 256; d <<= 1) {
    int t = (tid >= d) ? s[tid - d] : 0;
    __syncthreads();
    s[tid] += t;
    __syncthreads();
  }
  boff[tid] = s[tid] - v;
}

__global__ void k_scan3(const int* __restrict__ deg, const int* __restrict__ boff,
                        int* __restrict__ rowptr, int* __restrict__ cursor, int N) {
  __shared__ int s[256];
  int tid = threadIdx.x;
  int base = blockIdx.x * 1024 + tid * 4;
  int v[4]; int t = 0;
#pragma unroll
  for (int j = 0; j < 4; ++j) { int idx = base + j; v[j] = (idx < N) ? deg[idx] : 0; t += v[j]; }
  s[tid] = t; __syncthreads();
  for (int d = 1; d < 256; d <<= 1) {
    int u = (tid >= d) ? s[tid - d] : 0;
    __syncthreads();
    s[tid] += u;
    __syncthreads();
  }
  int run = boff[blockIdx.x] + s[tid] - t;  // exclusive prefix at base
#pragma unroll
  for (int j = 0; j < 4; ++j) {
    int idx = base + j;
    if (idx < N) { rowptr[idx] = run; cursor[idx] = run; }
    run += v[j];
    if (idx == N - 1) rowptr[N] = run;  // == E
  }
}

__global__ void k_scatter(const int* __restrict__ src, const int* __restrict__ dst,
                          int* __restrict__ cursor, int* __restrict__ col, int E) {
  int e = blockIdx.x * blockDim.x + threadIdx.x;
  if (e < E) {
    int pos = atomicAdd(&cursor[dst[e]], 1);
    col[pos] = src[e];
  }
}

// ---------------- aggregation: out = D^-1/2 (A+I) D^-1/2 x ----------------
// 30-feature version: 32 threads/node (2 idle lanes), 8 nodes/block
__global__ void k_agg30(const float* __restrict__ x, const float* __restrict__ dinv,
                        const int* __restrict__ rowptr, const int* __restrict__ col,
                        float* __restrict__ out, int N) {
  int node = blockIdx.x * 8 + (threadIdx.x >> 5);
  int f = threadIdx.x & 31;
  if (node >= N || f >= DIN) return;
  float di = dinv[node];
  float acc = x[(size_t)node * DIN + f] * di * di;  // self loop
  int e0 = rowptr[node], e1 = rowptr[node + 1];
  for (int e = e0; e < e1; ++e) {
    int c = col[e];
    acc += x[(size_t)c * DIN + f] * (dinv[c] * di);
  }
  out[(size_t)node * DIN + f] = acc;
}

// 128-feature version: 1 wave/node, float2 per lane (512B contiguous per gather)
__global__ void k_agg128(const float* __restrict__ h, const float* __restrict__ dinv,
                         const int* __restrict__ rowptr, const int* __restrict__ col,
                         float* __restrict__ out, int N) {
  int node = blockIdx.x * 4 + (threadIdx.x >> 6);
  if (node >= N) return;
  int lane = threadIdx.x & 63;
  const float2* hp = (const float2*)h;
  float di = dinv[node];
  float2 v = hp[(size_t)node * 64 + lane];
  float ws = di * di;
  float ax = v.x * ws, ay = v.y * ws;  // self loop
  int e0 = rowptr[node], e1 = rowptr[node + 1];
  for (int e = e0; e < e1; ++e) {
    int c = col[e];
    float wc = dinv[c] * di;
    float2 u = hp[(size_t)c * 64 + lane];
    ax = fmaf(u.x, wc, ax);
    ay = fmaf(u.y, wc, ay);
  }
  ((float2*)out)[(size_t)node * 64 + lane] = make_float2(ax, ay);
}

// ---------------- GEMM: C = relu(A @ W + b), W is [K,128] ----------------
// 64 rows/block, 256 threads, 4x8 micro-tile per thread.
// A tile staged transposed in LDS ([K][68] pad -> aligned b128, conflict-free);
// W streamed from global (64KB, L1/L2 resident).
__global__ __launch_bounds__(256) void k_gemm128(const float* __restrict__ A,
                                                 const float* __restrict__ W,
                                                 const float* __restrict__ b,
                                                 float* __restrict__ C, int N) {
  __shared__ float As[128][68];
  int tid = threadIdx.x;
  int rowBase = blockIdx.x * 64;
#pragma unroll
  for (int cth = 0; cth < 8; ++cth) {
    int linear = cth * 1024 + tid * 4;
    int r = linear >> 7;      // /128
    int k = linear & 127;
    int row = rowBase + r;
    float4 v = make_float4(0.f, 0.f, 0.f, 0.f);
    if (row < N) v = *(const float4*)(A + (size_t)row * 128 + k);
    As[k + 0][r] = v.x; As[k + 1][r] = v.y; As[k + 2][r] = v.z; As[k + 3][r] = v.w;
  }
  __syncthreads();
  int cg = tid & 15, rg = tid >> 4;
  int c0 = cg * 8, r0 = rg * 4;
  float acc[4][8] = {};
#pragma unroll 8
  for (int k = 0; k < 128; ++k) {
    float4 a4 = *(const float4*)&As[k][r0];
    float4 w0 = *(const float4*)(W + k * 128 + c0);
    float4 w1 = *(const float4*)(W + k * 128 + c0 + 4);
    float av[4] = {a4.x, a4.y, a4.z, a4.w};
    float wv[8] = {w0.x, w0.y, w0.z, w0.w, w1.x, w1.y, w1.z, w1.w};
#pragma unroll
    for (int r = 0; r < 4; ++r)
#pragma unroll
      for (int c = 0; c < 8; ++c)
        acc[r][c] = fmaf(av[r], wv[c], acc[r][c]);
  }
  float4 bl = *(const float4*)(b + c0);
  float4 bh = *(const float4*)(b + c0 + 4);
  float bv[8] = {bl.x, bl.y, bl.z, bl.w, bh.x, bh.y, bh.z, bh.w};
#pragma unroll
  for (int r = 0; r < 4; ++r) {
    int row = rowBase + r0 + r;
    if (row < N) {
      float o[8];
#pragma unroll
      for (int c = 0; c < 8; ++c) o[c] = fmaxf(acc[r][c] + bv[c], 0.f);
      *(float4*)(C + (size_t)row * 128 + c0)     = make_float4(o[0], o[1], o[2], o[3]);
      *(float4*)(C + (size_t)row * 128 + c0 + 4) = make_float4(o[4], o[5], o[6], o[7]);
    }
  }
}

__global__ __launch_bounds__(256) void k_gemm30(const float* __restrict__ A,
                                                const float* __restrict__ W,
                                                const float* __restrict__ b,
                                                float* __restrict__ C, int N) {
  __shared__ float As[DIN][68];
  int tid = threadIdx.x;
  int rowBase = blockIdx.x * 64;
  for (int idx = tid; idx < 64 * DIN; idx += 256) {
    int r = idx / DIN, k = idx - r * DIN;
    int row = rowBase + r;
    As[k][r] = (row < N) ? A[(size_t)row * DIN + k] : 0.f;
  }
  __syncthreads();
  int cg = tid & 15, rg = tid >> 4;
  int c0 = cg * 8, r0 = rg * 4;
  float acc[4][8] = {};
#pragma unroll
  for (int k = 0; k < DIN; ++k) {
    float4 a4 = *(const float4*)&As[k][r0];
    float4 w0 = *(const float4*)(W + k * 128 + c0);
    float4 w1 = *(const float4*)(W + k * 128 + c0 + 4);
    float av[4] = {a4.x, a4.y, a4.z, a4.w};
    float wv[8] = {w0.x, w0.y, w0.z, w0.w, w1.x, w1.y, w1.z, w1.w};
#pragma unroll
    for (int r = 0; r < 4; ++r)
#pragma unroll
      for (int c = 0; c < 8; ++c)
        acc[r][c] = fmaf(av[r], wv[c], acc[r][c]);
  }
  float4 bl = *(const float4*)(b + c0);
  float4 bh = *(const float4*)(b + c0 + 4);
  float bv[8] = {bl.x, bl.y, bl.z, bl.w, bh.x, bh.y, bh.z, bh.w};
#pragma unroll
  for (int r = 0; r < 4; ++r) {
    int row = rowBase + r0 + r;
    if (row < N) {
      float o[8];
#pragma unroll
      for (int c = 0; c < 8; ++c) o[c] = fmaxf(acc[r][c] + bv[c], 0.f);
      *(float4*)(C + (size_t)row * 128 + c0)     = make_float4(o[0], o[1], o[2], o[3]);
      *(float4*)(C + (size_t)row * 128 + c0 + 4) = make_float4(o[4], o[5], o[6], o[7]);
    }
  }
}

// ---------------- mean pool over sorted batch_idx ----------------
__global__ void k_pool(const float* __restrict__ h, const int* __restrict__ batch,
                       float* __restrict__ out, int N, int G) {
  int g = blockIdx.x;
  int tid = threadIdx.x;  // 128 threads = 1 feature each
  int lo = 0, hi = N;
  while (lo < hi) { int mid = (lo + hi) >> 1; if (batch[mid] < g) lo = mid + 1; else hi = mid; }
  int s = lo;
  hi = N;
  while (lo < hi) { int mid = (lo + hi) >> 1; if (batch[mid] < g + 1) lo = mid + 1; else hi = mid; }
  int e = lo;
  float acc = 0.f;
  for (int n = s; n < e; ++n) acc += h[(size_t)n * 128 + tid];
  float cnt = (float)(e - s);
  out[(size_t)g * 128 + tid] = acc / fmaxf(cnt, 1.f);
}

extern "C" void kernel_launch(void* const* d_in, const int* in_sizes, int n_in,
                              void* d_out, int out_size, void* d_ws, size_t ws_size,
                              hipStream_t stream) {
  const float* x  = (const float*)d_in[0];
  const int* ei   = (const int*)d_in[1];
  const int* batch = (const int*)d_in[2];
  const float* W1 = (const float*)d_in[3];
  const float* b1 = (const float*)d_in[4];
  const float* W2 = (const float*)d_in[5];
  const float* b2 = (const float*)d_in[6];
  const float* W3 = (const float*)d_in[7];
  const float* b3 = (const float*)d_in[8];
  float* out = (float*)d_out;
  int N = in_sizes[2];
  int E = in_sizes[1] / 2;
  int G = out_size / HD;
  const int* src = ei;
  const int* dst = ei + E;

  // workspace carve-up (~213 MB total)
  size_t off = 0;
  char* ws = (char*)d_ws;
  auto alloc = [&](size_t bytes) -> void* {
    void* p = ws + off;
    off += (bytes + 255) & ~(size_t)255;
    return p;
  };
  int*   deg    = (int*)alloc((size_t)N * 4);
  float* dinv   = (float*)alloc((size_t)N * 4);
  int*   rowptr = (int*)alloc((size_t)(N + 1) * 4);
  int*   cursor = (int*)alloc((size_t)N * 4);
  int*   col    = (int*)alloc((size_t)E * 4);
  int*   bsum   = (int*)alloc(256 * 4);
  int*   boff   = (int*)alloc(256 * 4);
  float* hA     = (float*)alloc((size_t)N * HD * 4);
  float* hB     = (float*)alloc((size_t)N * HD * 4);  // also holds the N x 30 agg of x
  (void)ws_size; (void)n_in;

  int nb1024 = (N + 1023) / 1024;
  k_zero_i32<<<(N + 255) / 256, 256, 0, stream>>>(deg, N);
  k_degree<<<(E + 255) / 256, 256, 0, stream>>>(dst, deg, E);
  k_dinv<<<(N + 255) / 256, 256, 0, stream>>>(deg, dinv, N);
  k_scan1<<<nb1024, 256, 0, stream>>>(deg, bsum, N);
  k_scan2<<<1, 256, 0, stream>>>(bsum, boff, nb1024);
  k_scan3<<<nb1024, 256, 0, stream>>>(deg, boff, rowptr, cursor, N);
  k_scatter<<<(E + 255) / 256, 256, 0, stream>>>(src, dst, cursor, col, E);

  // layer 1 (30-dim aggregate, then 30x128 GEMM)
  k_agg30<<<(N + 7) / 8, 256, 0, stream>>>(x, dinv, rowptr, col, hB, N);
  k_gemm30<<<(N + 63) / 64, 256, 0, stream>>>(hB, W1, b1, hA, N);
  // layer 2
  k_agg128<<<(N + 3) / 4, 256, 0, stream>>>(hA, dinv, rowptr, col, hB, N);
  k_gemm128<<<(N + 63) / 64, 256, 0, stream>>>(hB, W2, b2, hA, N);
  // layer 3
  k_agg128<<<(N + 3) / 4, 256, 0, stream>>>(hA, dinv, rowptr, col, hB, N);
  k_gemm128<<<(N + 63) / 64, 256, 0, stream>>>(hB, W3, b3, hA, N);
  // pool
  k_pool<<<G, 128, 0, stream>>>(hA, batch, out, N, G);
}

// Round 3
// 493.446 us; speedup vs baseline: 1.5472x; 1.5472x over previous
//
#include <hip/hip_runtime.h>

// 3-layer GCN + mean pool. bf16 storage / MFMA GEMM / fp32 accumulate.
// Pipeline:
//   deg -> dinv -> scan -> CSR scatter ; W1/W2/W3 transposed+cast to bf16
//   L1: agg30(x fp32 -> bf16 [N][32]) -> mfma gemm K=32  (+b1, relu) -> hA bf16
//   L2: agg128(bf16)                  -> mfma gemm K=128 (+b2, relu) -> hA
//   L3: agg128(bf16)                  -> mfma gemm K=128 (+b3, relu)
//   mean-pool (sorted batch_idx binary search), fp32 out
// Identity: S(XW) = (SX)W.  MFMA layouts (16x16x32 bf16, verified m89/m120):
//   A[m=lane&15][k=(lane>>4)*8+j], B[k=(lane>>4)*8+j][n=lane&15],
//   D[row=(lane>>4)*4+reg][col=lane&15]

#define DIN 30
#define HD  128

typedef __attribute__((ext_vector_type(8))) short v8s;
typedef __attribute__((ext_vector_type(4))) float v4f;

static __device__ __forceinline__ unsigned short f2bf(float f) {
  unsigned int u = __float_as_uint(f);
  u += 0x7fffu + ((u >> 16) & 1u);   // RNE
  return (unsigned short)(u >> 16);
}
static __device__ __forceinline__ float bf2f(unsigned short s) {
  return __uint_as_float(((unsigned int)s) << 16);
}

// ---------------- preprocessing ----------------
__global__ void k_zero_i32(int* __restrict__ p, int n) {
  int i = blockIdx.x * blockDim.x + threadIdx.x;
  if (i < n) p[i] = 0;
}

__global__ void k_degree(const int* __restrict__ dst, int* __restrict__ deg, int E) {
  int e = blockIdx.x * blockDim.x + threadIdx.x;
  if (e < E) atomicAdd(&deg[dst[e]], 1);
}

__global__ void k_dinv(const int* __restrict__ deg, float* __restrict__ dinv, int N) {
  int i = blockIdx.x * blockDim.x + threadIdx.x;
  if (i < N) dinv[i] = rsqrtf((float)(1 + deg[i]));
}

__global__ void k_scan1(const int* __restrict__ deg, int* __restrict__ bsum, int N) {
  __shared__ int s[256];
  int tid = threadIdx.x;
  int base = blockIdx.x * 1024 + tid * 4;
  int t = 0;
#pragma unroll
  for (int j = 0; j < 4; ++j) { int idx = base + j; if (idx < N) t += deg[idx]; }
  s[tid] = t; __syncthreads();
  for (int d = 128; d > 0; d >>= 1) { if (tid < d) s[tid] += s[tid + d]; __syncthreads(); }
  if (tid == 0) bsum[blockIdx.x] = s[0];
}

__global__ void k_scan2(const int* __restrict__ bsum, int* __restrict__ boff, int nb) {
  __shared__ int s[256];
  int tid = threadIdx.x;
  int v = (tid < nb) ? bsum[tid] : 0;
  s[tid] = v; __syncthreads();
  for (int d = 1; d < 256; d <<= 1) {
    int t = (tid >= d) ? s[tid - d] : 0;
    __syncthreads();
    s[tid] += t;
    __syncthreads();
  }
  boff[tid] = s[tid] - v;
}

__global__ void k_scan3(const int* __restrict__ deg, const int* __restrict__ boff,
                        int* __restrict__ rowptr, int* __restrict__ cursor, int N) {
  __shared__ int s[256];
  int tid = threadIdx.x;
  int base = blockIdx.x * 1024 + tid * 4;
  int v[4]; int t = 0;
#pragma unroll
  for (int j = 0; j < 4; ++j) { int idx = base + j; v[j] = (idx < N) ? deg[idx] : 0; t += v[j]; }
  s[tid] = t; __syncthreads();
  for (int d = 1; d < 256; d <<= 1) {
    int u = (tid >= d) ? s[tid - d] : 0;
    __syncthreads();
    s[tid] += u;
    __syncthreads();
  }
  int run = boff[blockIdx.x] + s[tid] - t;
#pragma unroll
  for (int j = 0; j < 4; ++j) {
    int idx = base + j;
    if (idx < N) { rowptr[idx] = run; cursor[idx] = run; }
    run += v[j];
    if (idx == N - 1) rowptr[N] = run;
  }
}

__global__ void k_scatter(const int* __restrict__ src, const int* __restrict__ dst,
                          int* __restrict__ cursor, int* __restrict__ col, int E) {
  int e = blockIdx.x * blockDim.x + threadIdx.x;
  if (e < E) {
    int pos = atomicAdd(&cursor[dst[e]], 1);
    col[pos] = src[e];
  }
}

// W [K][128] fp32 -> WT [128][Kstore] bf16 (zero-pad k >= Kreal)
__global__ void k_wt(const float* __restrict__ W, unsigned short* __restrict__ WT,
                     int Kreal, int Kstore) {
  int n = blockIdx.x;
  for (int k = threadIdx.x; k < Kstore; k += blockDim.x)
    WT[n * Kstore + k] = (k < Kreal) ? f2bf(W[k * 128 + n]) : (unsigned short)0;
}

// ---------------- aggregation ----------------
// 30-dim fp32 input -> bf16 [N][32] (k=30,31 zero)
__global__ void k_agg30(const float* __restrict__ x, const float* __restrict__ dinv,
                        const int* __restrict__ rowptr, const int* __restrict__ col,
                        unsigned short* __restrict__ out, int N) {
  int node = blockIdx.x * 8 + (threadIdx.x >> 5);
  int f = threadIdx.x & 31;
  if (node >= N) return;
  float acc = 0.f;
  if (f < DIN) {
    float di = dinv[node];
    acc = x[(size_t)node * DIN + f] * di * di;
    int e0 = rowptr[node], e1 = rowptr[node + 1];
    for (int e = e0; e < e1; ++e) {
      int c = col[e];
      acc += x[(size_t)c * DIN + f] * (dinv[c] * di);
    }
  }
  out[(size_t)node * 32 + f] = f2bf(acc);
}

// 128-dim bf16 in/out, fp32 accumulate; 1 wave/node, 2 features/lane (uint load)
__global__ void k_agg128(const unsigned short* __restrict__ h, const float* __restrict__ dinv,
                         const int* __restrict__ rowptr, const int* __restrict__ col,
                         unsigned short* __restrict__ out, int N) {
  int node = blockIdx.x * 4 + (threadIdx.x >> 6);
  if (node >= N) return;
  int lane = threadIdx.x & 63;
  const unsigned int* hp = (const unsigned int*)h;
  float di = dinv[node];
  unsigned int u = hp[(size_t)node * 64 + lane];
  float ws = di * di;
  float ax = __uint_as_float(u << 16) * ws;
  float ay = __uint_as_float(u & 0xffff0000u) * ws;
  int e0 = rowptr[node], e1 = rowptr[node + 1];
  for (int e = e0; e < e1; ++e) {
    int c = col[e];
    float wc = dinv[c] * di;
    unsigned int v = hp[(size_t)c * 64 + lane];
    ax = fmaf(__uint_as_float(v << 16), wc, ax);
    ay = fmaf(__uint_as_float(v & 0xffff0000u), wc, ay);
  }
  unsigned int o = (unsigned int)f2bf(ax) | ((unsigned int)f2bf(ay) << 16);
  ((unsigned int*)out)[(size_t)node * 64 + lane] = o;
}

// ---------------- MFMA GEMM: C = relu(A @ WT^T + b), bf16 ----------------
// A [N][K] bf16, WT [128][K] bf16, C [N][128] bf16. Block: 64 rows, 4 waves.
template <int K>
__global__ __launch_bounds__(256) void k_gemm_mfma(const unsigned short* __restrict__ A,
                                                   const unsigned short* __restrict__ WT,
                                                   const float* __restrict__ b,
                                                   unsigned short* __restrict__ C, int N) {
  constexpr int KP = (K == 128) ? 136 : 40;  // +pad: row stride 272/80 B, 16B-aligned, 2-way banks
  __shared__ unsigned short As[64][KP];
  __shared__ unsigned short Ws[128][KP];
  int tid = threadIdx.x;
  int rowBase = blockIdx.x * 64;

  constexpr int SEGS = K / 8;        // 16B segments per row
  constexpr int RA = 256 / SEGS;     // rows staged per iteration
  int r = tid / SEGS, seg = tid % SEGS;
#pragma unroll
  for (int it = 0; it < 64 / RA; ++it) {
    int row = it * RA + r;
    uint4 v = make_uint4(0u, 0u, 0u, 0u);
    if (rowBase + row < N) v = *(const uint4*)(A + (size_t)(rowBase + row) * K + seg * 8);
    *(uint4*)&As[row][seg * 8] = v;
  }
#pragma unroll
  for (int it = 0; it < 128 / RA; ++it) {
    int row = it * RA + r;
    *(uint4*)&Ws[row][seg * 8] = *(const uint4*)(WT + (size_t)row * K + seg * 8);
  }
  __syncthreads();

  int wv = tid >> 6, lane = tid & 63, quad = lane >> 4, l15 = lane & 15;
  v8s afrag[K / 32];
#pragma unroll
  for (int kk = 0; kk < K / 32; ++kk)
    afrag[kk] = *(const v8s*)&As[wv * 16 + l15][kk * 32 + quad * 8];

#pragma unroll
  for (int t = 0; t < 8; ++t) {
    v4f acc = {0.f, 0.f, 0.f, 0.f};
#pragma unroll
    for (int kk = 0; kk < K / 32; ++kk) {
      v8s bfrag = *(const v8s*)&Ws[t * 16 + l15][kk * 32 + quad * 8];
      acc = __builtin_amdgcn_mfma_f32_16x16x32_bf16(afrag[kk], bfrag, acc, 0, 0, 0);
    }
    float bias = b[t * 16 + l15];
#pragma unroll
    for (int i = 0; i < 4; ++i) {
      int node = rowBase + wv * 16 + quad * 4 + i;
      if (node < N) {
        float o = fmaxf(acc[i] + bias, 0.f);
        C[(size_t)node * 128 + t * 16 + l15] = f2bf(o);
      }
    }
  }
}

// ---------------- mean pool over sorted batch_idx ----------------
__global__ void k_pool(const unsigned short* __restrict__ h, const int* __restrict__ batch,
                       float* __restrict__ out, int N, int G) {
  int g = blockIdx.x;
  int tid = threadIdx.x;  // 128 threads = 1 feature each
  int lo = 0, hi = N;
  while (lo < hi) { int mid = (lo + hi) >> 1; if (batch[mid] < g) lo = mid + 1; else hi = mid; }
  int s = lo;
  hi = N;
  while (lo < hi) { int mid = (lo + hi) >> 1; if (batch[mid] < g + 1) lo = mid + 1; else hi = mid; }
  int e = lo;
  float acc = 0.f;
  for (int n = s; n < e; ++n) acc += bf2f(h[(size_t)n * 128 + tid]);
  float cnt = (float)(e - s);
  out[(size_t)g * 128 + tid] = acc / fmaxf(cnt, 1.f);
}

extern "C" void kernel_launch(void* const* d_in, const int* in_sizes, int n_in,
                              void* d_out, int out_size, void* d_ws, size_t ws_size,
                              hipStream_t stream) {
  const float* x  = (const float*)d_in[0];
  const int* ei   = (const int*)d_in[1];
  const int* batch = (const int*)d_in[2];
  const float* W1 = (const float*)d_in[3];
  const float* b1 = (const float*)d_in[4];
  const float* W2 = (const float*)d_in[5];
  const float* b2 = (const float*)d_in[6];
  const float* W3 = (const float*)d_in[7];
  const float* b3 = (const float*)d_in[8];
  float* out = (float*)d_out;
  int N = in_sizes[2];
  int E = in_sizes[1] / 2;
  int G = out_size / HD;
  const int* src = ei;
  const int* dst = ei + E;

  size_t off = 0;
  char* ws = (char*)d_ws;
  auto alloc = [&](size_t bytes) -> void* {
    void* p = ws + off;
    off += (bytes + 255) & ~(size_t)255;
    return p;
  };
  int*   deg    = (int*)alloc((size_t)N * 4);
  float* dinv   = (float*)alloc((size_t)N * 4);
  int*   rowptr = (int*)alloc((size_t)(N + 1) * 4);
  int*   cursor = (int*)alloc((size_t)N * 4);
  int*   col    = (int*)alloc((size_t)E * 4);
  int*   bsum   = (int*)alloc(256 * 4);
  int*   boff   = (int*)alloc(256 * 4);
  unsigned short* xagg = (unsigned short*)alloc((size_t)N * 32 * 2);   // agg30 out, bf16
  unsigned short* hA   = (unsigned short*)alloc((size_t)N * HD * 2);   // bf16
  unsigned short* hB   = (unsigned short*)alloc((size_t)N * HD * 2);   // bf16
  unsigned short* W1T  = (unsigned short*)alloc(128 * 32 * 2);
  unsigned short* W2T  = (unsigned short*)alloc(128 * 128 * 2);
  unsigned short* W3T  = (unsigned short*)alloc(128 * 128 * 2);
  (void)ws_size; (void)n_in;

  int nb1024 = (N + 1023) / 1024;
  k_zero_i32<<<(N + 255) / 256, 256, 0, stream>>>(deg, N);
  k_degree<<<(E + 255) / 256, 256, 0, stream>>>(dst, deg, E);
  k_dinv<<<(N + 255) / 256, 256, 0, stream>>>(deg, dinv, N);
  k_scan1<<<nb1024, 256, 0, stream>>>(deg, bsum, N);
  k_scan2<<<1, 256, 0, stream>>>(bsum, boff, nb1024);
  k_scan3<<<nb1024, 256, 0, stream>>>(deg, boff, rowptr, cursor, N);
  k_scatter<<<(E + 255) / 256, 256, 0, stream>>>(src, dst, cursor, col, E);
  k_wt<<<128, 128, 0, stream>>>(W1, W1T, DIN, 32);
  k_wt<<<128, 128, 0, stream>>>(W2, W2T, 128, 128);
  k_wt<<<128, 128, 0, stream>>>(W3, W3T, 128, 128);

  int gemmBlocks = (N + 63) / 64;
  // layer 1
  k_agg30<<<(N + 7) / 8, 256, 0, stream>>>(x, dinv, rowptr, col, xagg, N);
  k_gemm_mfma<32><<<gemmBlocks, 256, 0, stream>>>(xagg, W1T, b1, hA, N);
  // layer 2
  k_agg128<<<(N + 3) / 4, 256, 0, stream>>>(hA, dinv, rowptr, col, hB, N);
  k_gemm_mfma<128><<<gemmBlocks, 256, 0, stream>>>(hB, W2T, b2, hA, N);
  // layer 3
  k_agg128<<<(N + 3) / 4, 256, 0, stream>>>(hA, dinv, rowptr, col, hB, N);
  k_gemm_mfma<128><<<gemmBlocks, 256, 0, stream>>>(hB, W3T, b3, hA, N);
  // pool
  k_pool<<<G, 128, 0, stream>>>(hA, batch, out, N, G);
}

// Round 4
// 390.577 us; speedup vs baseline: 1.9546x; 1.2634x over previous
//
#include <hip/hip_runtime.h>

// 3-layer GCN + mean pool. bf16 storage / MFMA GEMM / fp32 accumulate.
// R4: latency-optimized aggregation — 16 lanes/node x 4 nodes/wave,
// 2-way edge unroll, per-edge weight precomputed into packed (col,w) uint2.

#define DIN 30
#define HD  128

typedef __attribute__((ext_vector_type(8))) short v8s;
typedef __attribute__((ext_vector_type(4))) float v4f;

static __device__ __forceinline__ unsigned short f2bf(float f) {
  unsigned int u = __float_as_uint(f);
  u += 0x7fffu + ((u >> 16) & 1u);   // RNE
  return (unsigned short)(u >> 16);
}
static __device__ __forceinline__ float bf2f(unsigned short s) {
  return __uint_as_float(((unsigned int)s) << 16);
}
static __device__ __forceinline__ float bflo(unsigned int u) {
  return __uint_as_float(u << 16);
}
static __device__ __forceinline__ float bfhi(unsigned int u) {
  return __uint_as_float(u & 0xffff0000u);
}

// ---------------- preprocessing ----------------
__global__ void k_zero_i32(int* __restrict__ p, int n) {
  int i = blockIdx.x * blockDim.x + threadIdx.x;
  if (i < n) p[i] = 0;
}

__global__ void k_degree(const int* __restrict__ dst, int* __restrict__ deg, int E) {
  int e = blockIdx.x * blockDim.x + threadIdx.x;
  if (e < E) atomicAdd(&deg[dst[e]], 1);
}

__global__ void k_dinv(const int* __restrict__ deg, float* __restrict__ dinv, int N) {
  int i = blockIdx.x * blockDim.x + threadIdx.x;
  if (i < N) dinv[i] = rsqrtf((float)(1 + deg[i]));
}

__global__ void k_scan1(const int* __restrict__ deg, int* __restrict__ bsum, int N) {
  __shared__ int s[256];
  int tid = threadIdx.x;
  int base = blockIdx.x * 1024 + tid * 4;
  int t = 0;
#pragma unroll
  for (int j = 0; j < 4; ++j) { int idx = base + j; if (idx < N) t += deg[idx]; }
  s[tid] = t; __syncthreads();
  for (int d = 128; d > 0; d >>= 1) { if (tid < d) s[tid] += s[tid + d]; __syncthreads(); }
  if (tid == 0) bsum[blockIdx.x] = s[0];
}

__global__ void k_scan2(const int* __restrict__ bsum, int* __restrict__ boff, int nb) {
  __shared__ int s[256];
  int tid = threadIdx.x;
  int v = (tid < nb) ? bsum[tid] : 0;
  s[tid] = v; __syncthreads();
  for (int d = 1; d < 256; d <<= 1) {
    int t = (tid >= d) ? s[tid - d] : 0;
    __syncthreads();
    s[tid] += t;
    __syncthreads();
  }
  boff[tid] = s[tid] - v;
}

__global__ void k_scan3(const int* __restrict__ deg, const int* __restrict__ boff,
                        int* __restrict__ rowptr, int* __restrict__ cursor, int N) {
  __shared__ int s[256];
  int tid = threadIdx.x;
  int base = blockIdx.x * 1024 + tid * 4;
  int v[4]; int t = 0;
#pragma unroll
  for (int j = 0; j < 4; ++j) { int idx = base + j; v[j] = (idx < N) ? deg[idx] : 0; t += v[j]; }
  s[tid] = t; __syncthreads();
  for (int d = 1; d < 256; d <<= 1) {
    int u = (tid >= d) ? s[tid - d] : 0;
    __syncthreads();
    s[tid] += u;
    __syncthreads();
  }
  int run = boff[blockIdx.x] + s[tid] - t;
#pragma unroll
  for (int j = 0; j < 4; ++j) {
    int idx = base + j;
    if (idx < N) { rowptr[idx] = run; cursor[idx] = run; }
    run += v[j];
    if (idx == N - 1) rowptr[N] = run;
  }
}

// CSR scatter with fused per-edge weight: ecw[pos] = (src, dinv[src]*dinv[dst])
__global__ void k_scatter(const int* __restrict__ src, const int* __restrict__ dst,
                          const float* __restrict__ dinv,
                          int* __restrict__ cursor, uint2* __restrict__ ecw, int E) {
  int e = blockIdx.x * blockDim.x + threadIdx.x;
  if (e < E) {
    int s = src[e], d = dst[e];
    int pos = atomicAdd(&cursor[d], 1);
    float w = dinv[s] * dinv[d];
    ecw[pos] = make_uint2((unsigned int)s, __float_as_uint(w));
  }
}

// W [K][128] fp32 -> WT [128][Kstore] bf16 (zero-pad k >= Kreal)
__global__ void k_wt(const float* __restrict__ W, unsigned short* __restrict__ WT,
                     int Kreal, int Kstore) {
  int n = blockIdx.x;
  for (int k = threadIdx.x; k < Kstore; k += blockDim.x)
    WT[n * Kstore + k] = (k < Kreal) ? f2bf(W[k * 128 + n]) : (unsigned short)0;
}

// ---------------- aggregation ----------------
// L1: 30-dim fp32 input -> bf16 [N][32]. 16 lanes/node (float2/lane), 16 nodes/block.
__global__ void k_agg30(const float* __restrict__ x, const float* __restrict__ dinv,
                        const int* __restrict__ rowptr, const uint2* __restrict__ ecw,
                        unsigned short* __restrict__ out, int N) {
  int node = blockIdx.x * 16 + (threadIdx.x >> 4);
  if (node >= N) return;
  int l16 = threadIdx.x & 15;
  int f = l16 * 2;
  bool valid = (f < DIN);            // lane 15 covers padded features 30,31
  float di = dinv[node];
  float ws = di * di;
  float a0 = 0.f, a1 = 0.f;
  if (valid) {
    float2 v = *(const float2*)(x + (size_t)node * DIN + f);
    a0 = v.x * ws; a1 = v.y * ws;
  }
  int e0 = rowptr[node], e1 = rowptr[node + 1];
  int e = e0;
  for (; e + 2 <= e1; e += 2) {
    uint2 p0 = ecw[e], p1 = ecw[e + 1];
    float w0 = __uint_as_float(p0.y), w1 = __uint_as_float(p1.y);
    if (valid) {
      float2 v0 = *(const float2*)(x + (size_t)p0.x * DIN + f);
      float2 v1 = *(const float2*)(x + (size_t)p1.x * DIN + f);
      a0 = fmaf(v0.x, w0, a0); a1 = fmaf(v0.y, w0, a1);
      a0 = fmaf(v1.x, w1, a0); a1 = fmaf(v1.y, w1, a1);
    }
  }
  if (e < e1) {
    uint2 p0 = ecw[e];
    float w0 = __uint_as_float(p0.y);
    if (valid) {
      float2 v0 = *(const float2*)(x + (size_t)p0.x * DIN + f);
      a0 = fmaf(v0.x, w0, a0); a1 = fmaf(v0.y, w0, a1);
    }
  }
  unsigned int o = (unsigned int)f2bf(a0) | ((unsigned int)f2bf(a1) << 16);
  ((unsigned int*)out)[(size_t)node * 16 + l16] = o;
}

// L2/L3: 128-dim bf16 in/out. 16 lanes/node (uint4 = 8 bf16/lane), 16 nodes/block,
// 2-way edge unroll -> up to 8 independent gathers in flight per wave.
__global__ void k_agg128(const unsigned short* __restrict__ h, const float* __restrict__ dinv,
                         const int* __restrict__ rowptr, const uint2* __restrict__ ecw,
                         unsigned short* __restrict__ out, int N) {
  int node = blockIdx.x * 16 + (threadIdx.x >> 4);
  if (node >= N) return;
  int l16 = threadIdx.x & 15;
  const uint4* hp = (const uint4*)h;   // 16 uint4 per 128-feature row
  float di = dinv[node];
  float ws = di * di;
  uint4 u = hp[(size_t)node * 16 + l16];
  float a0 = bflo(u.x) * ws, a1 = bfhi(u.x) * ws;
  float a2 = bflo(u.y) * ws, a3 = bfhi(u.y) * ws;
  float a4 = bflo(u.z) * ws, a5 = bfhi(u.z) * ws;
  float a6 = bflo(u.w) * ws, a7 = bfhi(u.w) * ws;
  int e0 = rowptr[node], e1 = rowptr[node + 1];
  int e = e0;
  for (; e + 2 <= e1; e += 2) {
    uint2 p0 = ecw[e], p1 = ecw[e + 1];
    uint4 v0 = hp[(size_t)p0.x * 16 + l16];
    uint4 v1 = hp[(size_t)p1.x * 16 + l16];
    float w0 = __uint_as_float(p0.y), w1 = __uint_as_float(p1.y);
    a0 = fmaf(bflo(v0.x), w0, a0); a1 = fmaf(bfhi(v0.x), w0, a1);
    a2 = fmaf(bflo(v0.y), w0, a2); a3 = fmaf(bfhi(v0.y), w0, a3);
    a4 = fmaf(bflo(v0.z), w0, a4); a5 = fmaf(bfhi(v0.z), w0, a5);
    a6 = fmaf(bflo(v0.w), w0, a6); a7 = fmaf(bfhi(v0.w), w0, a7);
    a0 = fmaf(bflo(v1.x), w1, a0); a1 = fmaf(bfhi(v1.x), w1, a1);
    a2 = fmaf(bflo(v1.y), w1, a2); a3 = fmaf(bfhi(v1.y), w1, a3);
    a4 = fmaf(bflo(v1.z), w1, a4); a5 = fmaf(bfhi(v1.z), w1, a5);
    a6 = fmaf(bflo(v1.w), w1, a6); a7 = fmaf(bfhi(v1.w), w1, a7);
  }
  if (e < e1) {
    uint2 p0 = ecw[e];
    uint4 v0 = hp[(size_t)p0.x * 16 + l16];
    float w0 = __uint_as_float(p0.y);
    a0 = fmaf(bflo(v0.x), w0, a0); a1 = fmaf(bfhi(v0.x), w0, a1);
    a2 = fmaf(bflo(v0.y), w0, a2); a3 = fmaf(bfhi(v0.y), w0, a3);
    a4 = fmaf(bflo(v0.z), w0, a4); a5 = fmaf(bfhi(v0.z), w0, a5);
    a6 = fmaf(bflo(v0.w), w0, a6); a7 = fmaf(bfhi(v0.w), w0, a7);
  }
  uint4 o;
  o.x = (unsigned int)f2bf(a0) | ((unsigned int)f2bf(a1) << 16);
  o.y = (unsigned int)f2bf(a2) | ((unsigned int)f2bf(a3) << 16);
  o.z = (unsigned int)f2bf(a4) | ((unsigned int)f2bf(a5) << 16);
  o.w = (unsigned int)f2bf(a6) | ((unsigned int)f2bf(a7) << 16);
  ((uint4*)out)[(size_t)node * 16 + l16] = o;
}

// ---------------- MFMA GEMM: C = relu(A @ WT^T + b), bf16 ----------------
template <int K>
__global__ __launch_bounds__(256) void k_gemm_mfma(const unsigned short* __restrict__ A,
                                                   const unsigned short* __restrict__ WT,
                                                   const float* __restrict__ b,
                                                   unsigned short* __restrict__ C, int N) {
  constexpr int KP = (K == 128) ? 136 : 40;
  __shared__ unsigned short As[64][KP];
  __shared__ unsigned short Ws[128][KP];
  int tid = threadIdx.x;
  int rowBase = blockIdx.x * 64;

  constexpr int SEGS = K / 8;
  constexpr int RA = 256 / SEGS;
  int r = tid / SEGS, seg = tid % SEGS;
#pragma unroll
  for (int it = 0; it < 64 / RA; ++it) {
    int row = it * RA + r;
    uint4 v = make_uint4(0u, 0u, 0u, 0u);
    if (rowBase + row < N) v = *(const uint4*)(A + (size_t)(rowBase + row) * K + seg * 8);
    *(uint4*)&As[row][seg * 8] = v;
  }
#pragma unroll
  for (int it = 0; it < 128 / RA; ++it) {
    int row = it * RA + r;
    *(uint4*)&Ws[row][seg * 8] = *(const uint4*)(WT + (size_t)row * K + seg * 8);
  }
  __syncthreads();

  int wv = tid >> 6, lane = tid & 63, quad = lane >> 4, l15 = lane & 15;
  v8s afrag[K / 32];
#pragma unroll
  for (int kk = 0; kk < K / 32; ++kk)
    afrag[kk] = *(const v8s*)&As[wv * 16 + l15][kk * 32 + quad * 8];

#pragma unroll
  for (int t = 0; t < 8; ++t) {
    v4f acc = {0.f, 0.f, 0.f, 0.f};
#pragma unroll
    for (int kk = 0; kk < K / 32; ++kk) {
      v8s bfrag = *(const v8s*)&Ws[t * 16 + l15][kk * 32 + quad * 8];
      acc = __builtin_amdgcn_mfma_f32_16x16x32_bf16(afrag[kk], bfrag, acc, 0, 0, 0);
    }
    float bias = b[t * 16 + l15];
#pragma unroll
    for (int i = 0; i < 4; ++i) {
      int node = rowBase + wv * 16 + quad * 4 + i;
      if (node < N) {
        float o = fmaxf(acc[i] + bias, 0.f);
        C[(size_t)node * 128 + t * 16 + l15] = f2bf(o);
      }
    }
  }
}

// ---------------- mean pool over sorted batch_idx ----------------
__global__ void k_pool(const unsigned short* __restrict__ h, const int* __restrict__ batch,
                       float* __restrict__ out, int N, int G) {
  int g = blockIdx.x;
  int tid = threadIdx.x;
  int lo = 0, hi = N;
  while (lo < hi) { int mid = (lo + hi) >> 1; if (batch[mid] < g) lo = mid + 1; else hi = mid; }
  int s = lo;
  hi = N;
  while (lo < hi) { int mid = (lo + hi) >> 1; if (batch[mid] < g + 1) lo = mid + 1; else hi = mid; }
  int e = lo;
  float acc = 0.f;
  for (int n = s; n < e; ++n) acc += bf2f(h[(size_t)n * 128 + tid]);
  float cnt = (float)(e - s);
  out[(size_t)g * 128 + tid] = acc / fmaxf(cnt, 1.f);
}

extern "C" void kernel_launch(void* const* d_in, const int* in_sizes, int n_in,
                              void* d_out, int out_size, void* d_ws, size_t ws_size,
                              hipStream_t stream) {
  const float* x  = (const float*)d_in[0];
  const int* ei   = (const int*)d_in[1];
  const int* batch = (const int*)d_in[2];
  const float* W1 = (const float*)d_in[3];
  const float* b1 = (const float*)d_in[4];
  const float* W2 = (const float*)d_in[5];
  const float* b2 = (const float*)d_in[6];
  const float* W3 = (const float*)d_in[7];
  const float* b3 = (const float*)d_in[8];
  float* out = (float*)d_out;
  int N = in_sizes[2];
  int E = in_sizes[1] / 2;
  int G = out_size / HD;
  const int* src = ei;
  const int* dst = ei + E;

  size_t off = 0;
  char* ws = (char*)d_ws;
  auto alloc = [&](size_t bytes) -> void* {
    void* p = ws + off;
    off += (bytes + 255) & ~(size_t)255;
    return p;
  };
  int*   deg    = (int*)alloc((size_t)N * 4);
  float* dinv   = (float*)alloc((size_t)N * 4);
  int*   rowptr = (int*)alloc((size_t)(N + 1) * 4);
  int*   cursor = (int*)alloc((size_t)N * 4);
  uint2* ecw    = (uint2*)alloc((size_t)E * 8);
  int*   bsum   = (int*)alloc(256 * 4);
  int*   boff   = (int*)alloc(256 * 4);
  unsigned short* xagg = (unsigned short*)alloc((size_t)N * 32 * 2);
  unsigned short* hA   = (unsigned short*)alloc((size_t)N * HD * 2);
  unsigned short* hB   = (unsigned short*)alloc((size_t)N * HD * 2);
  unsigned short* W1T  = (unsigned short*)alloc(128 * 32 * 2);
  unsigned short* W2T  = (unsigned short*)alloc(128 * 128 * 2);
  unsigned short* W3T  = (unsigned short*)alloc(128 * 128 * 2);
  (void)ws_size; (void)n_in;

  int nb1024 = (N + 1023) / 1024;
  k_zero_i32<<<(N + 255) / 256, 256, 0, stream>>>(deg, N);
  k_degree<<<(E + 255) / 256, 256, 0, stream>>>(dst, deg, E);
  k_dinv<<<(N + 255) / 256, 256, 0, stream>>>(deg, dinv, N);
  k_scan1<<<nb1024, 256, 0, stream>>>(deg, bsum, N);
  k_scan2<<<1, 256, 0, stream>>>(bsum, boff, nb1024);
  k_scan3<<<nb1024, 256, 0, stream>>>(deg, boff, rowptr, cursor, N);
  k_scatter<<<(E + 255) / 256, 256, 0, stream>>>(src, dst, dinv, cursor, ecw, E);
  k_wt<<<128, 128, 0, stream>>>(W1, W1T, DIN, 32);
  k_wt<<<128, 128, 0, stream>>>(W2, W2T, 128, 128);
  k_wt<<<128, 128, 0, stream>>>(W3, W3T, 128, 128);

  int gemmBlocks = (N + 63) / 64;
  int aggBlocks = (N + 15) / 16;
  // layer 1
  k_agg30<<<aggBlocks, 256, 0, stream>>>(x, dinv, rowptr, ecw, xagg, N);
  k_gemm_mfma<32><<<gemmBlocks, 256, 0, stream>>>(xagg, W1T, b1, hA, N);
  // layer 2
  k_agg128<<<aggBlocks, 256, 0, stream>>>(hA, dinv, rowptr, ecw, hB, N);
  k_gemm_mfma<128><<<gemmBlocks, 256, 0, stream>>>(hB, W2T, b2, hA, N);
  // layer 3
  k_agg128<<<aggBlocks, 256, 0, stream>>>(hA, dinv, rowptr, ecw, hB, N);
  k_gemm_mfma<128><<<gemmBlocks, 256, 0, stream>>>(hB, W3T, b3, hA, N);
  // pool
  k_pool<<<G, 128, 0, stream>>>(hA, batch, out, N, G);
}